// Round 7
// baseline (109.782 us; speedup 1.0000x reference)
//
#include <hip/hip_runtime.h>
#include <cstdint>

#define B_ROWS   32768
#define D_DIM    512
#define NBLOCKS  512             // 2 blocks/CU, all resident
#define TPB      256             // 4 waves per block
#define WPB      (TPB / 64)
#define NWAVES   (NBLOCKS * WPB)          // 2048
#define RPW      (B_ROWS / NWAVES)        // 16 rows per wave, exact
#define STRIDE_B 4194304ULL               // NWAVES * 2048 bytes

struct Ws {
    unsigned anchor_idx;   // written by find_anchor
    int      done;         // init -1; last block sees old == NBLOCKS-2
};
// partials at (float*)d_ws + 64 : [NBLOCKS][12] (pos[4], neg[4], cnt0, pad)

typedef float f32x4 __attribute__((ext_vector_type(4)));

// Hand-placed waitcnt + scheduling fence (guide rule #18).
#define WAITVM(N) do { asm volatile("s_waitcnt vmcnt(" #N ")" ::: "memory"); \
                       __builtin_amdgcn_sched_barrier(0); } while (0)

// Volatile-asm 16B load: compiler cannot serialize or rematerialize it.
__device__ __forceinline__ void ld4(f32x4& d, uint64_t a) {
    asm volatile("global_load_dwordx4 %0, %1, off" : "=&v"(d) : "v"(a) : "memory");
}

__device__ __forceinline__ float dot4(f32x4 a, f32x4 b) {
    return a[0] * b[0] + a[1] * b[1] + a[2] * b[2] + a[3] * b[3];
}

// Reduce 8 independent per-lane values over 64 lanes with 11 shuffles.
// Lane group g=(lane>>3) ends holding the total of value j=g.
__device__ __forceinline__ float fold_reduce8(const float v[8], int lane) {
    float w[4];
    #pragma unroll
    for (int i = 0; i < 4; ++i) {
        float send = (lane & 32) ? v[i] : v[i + 4];
        float rcv  = __shfl_xor(send, 32);
        w[i] = ((lane & 32) ? v[i + 4] : v[i]) + rcv;
    }
    float u[2];
    #pragma unroll
    for (int i = 0; i < 2; ++i) {
        float send = (lane & 16) ? w[i] : w[i + 2];
        float rcv  = __shfl_xor(send, 16);
        u[i] = ((lane & 16) ? w[i + 2] : w[i]) + rcv;
    }
    float t;
    {
        float send = (lane & 8) ? u[0] : u[1];
        float rcv  = __shfl_xor(send, 8);
        t = ((lane & 8) ? u[1] : u[0]) + rcv;
    }
    t += __shfl_xor(t, 4);
    t += __shfl_xor(t, 2);
    t += __shfl_xor(t, 1);
    return t;
}

// ------------------------------------------------- early-exit anchor finder
__global__ void find_anchor_kernel(const int* __restrict__ label, Ws* ws) {
    __shared__ unsigned smin[4];
    __shared__ unsigned sres;
    const int t = threadIdx.x, lane = t & 63, wid = t >> 6;
    for (unsigned base = 0; base < B_ROWS; base += 1024) {
        int4 v = ((const int4*)label)[(base >> 2) + t];
        unsigned idx = base + (unsigned)t * 4;
        unsigned my = 0xFFFFFFFFu;
        if (v.w == 0) my = idx + 3;
        if (v.z == 0) my = idx + 2;
        if (v.y == 0) my = idx + 1;
        if (v.x == 0) my = idx;
        #pragma unroll
        for (int off = 32; off; off >>= 1) {
            unsigned o = (unsigned)__shfl_xor((int)my, off);
            my = my < o ? my : o;
        }
        if (lane == 0) smin[wid] = my;
        __syncthreads();
        if (t == 0) {
            unsigned m = min(min(smin[0], smin[1]), min(smin[2], smin[3]));
            sres = m;
            if (m != 0xFFFFFFFFu) ws->anchor_idx = m;
        }
        __syncthreads();
        if (sres != 0xFFFFFFFFu) return;   // uniform exit (typically 1st chunk)
        __syncthreads();
    }
}

// ------------------------------------------------- main pass (+ fused tail)
#define CONSUME(BUF, K, REISSUE)                                              \
  {                                                                           \
    float v[8];                                                               \
    _Pragma("unroll")                                                         \
    for (int m = 0; m < 4; ++m) {                                             \
      v[m]     = dot4(BUF[2*m], an[2*m])  + dot4(BUF[2*m+1], an[2*m+1]);      \
      v[m + 4] = dot4(BUF[2*m], BUF[2*m]) + dot4(BUF[2*m+1], BUF[2*m+1]);     \
    }                                                                         \
    __builtin_amdgcn_sched_barrier(0);                                        \
    if (REISSUE) {                                                            \
      _Pragma("unroll")                                                       \
      for (int j = 0; j < 8; ++j) { ld4(BUF[j], a[j]); a[j] += STRIDE_B; }    \
    }                                                                         \
    __builtin_amdgcn_sched_barrier(0);                                        \
    float t_ = fold_reduce8(v, lane);                                         \
    float other_ = __shfl_xor(t_, 32);                                        \
    unsigned r_ = gwave + (unsigned)(K) * NWAVES;                             \
    if (((lane & 39) == 0) && (r_ != aidx)) {                                 \
      float c_ = t_ * rsqrtf(other_) * inv_mine;                              \
      if (lab[K] == 0) posAcc += c_; else negAcc += c_;                       \
    }                                                                         \
  }

__launch_bounds__(TPB, 2)
__global__ void cos_accum_kernel(const int* __restrict__ label,
                                 const float* __restrict__ p_t,
                                 const float* __restrict__ p_a,
                                 const float* __restrict__ s_t,
                                 const float* __restrict__ s_a,
                                 Ws* ws,
                                 float* __restrict__ partials,
                                 float* __restrict__ out) {
    const float* X[4] = {p_t, p_a, s_t, s_a};
    __shared__ float red[WPB][12];
    __shared__ float fin[256];
    __shared__ float colsum[9];
    __shared__ int   slast;

    const unsigned aidx = ws->anchor_idx;
    const int lane = threadIdx.x & 63;
    const int wid  = threadIdx.x >> 6;
    const unsigned gwave = (unsigned)blockIdx.x * WPB + (unsigned)wid;

    // per-lane 64-bit addresses for the 8 loads of a row
    uint64_t a[8];
    #pragma unroll
    for (int m = 0; m < 4; ++m) {
        uint64_t base = (uint64_t)(uintptr_t)X[m]
                      + (uint64_t)gwave * (D_DIM * 4) + (uint64_t)lane * 16;
        a[2 * m]     = base;
        a[2 * m + 1] = base + 1024;
    }

    // anchor loads first (oldest vmcnt slots), then rows 0 and 1: 24 in flight
    f32x4 an[8], xa[8], xb[8];
    #pragma unroll
    for (int m = 0; m < 4; ++m) {
        uint64_t ab = (uint64_t)(uintptr_t)X[m]
                    + (uint64_t)aidx * (D_DIM * 4) + (uint64_t)lane * 16;
        ld4(an[2 * m], ab);
        ld4(an[2 * m + 1], ab + 1024);
    }
    #pragma unroll
    for (int j = 0; j < 8; ++j) { ld4(xa[j], a[j]); a[j] += STRIDE_B; }
    #pragma unroll
    for (int j = 0; j < 8; ++j) { ld4(xb[j], a[j]); a[j] += STRIDE_B; }

    // labels via wave-uniform scalar loads (lgkm path, vmcnt untouched)
    int lab[RPW];
    #pragma unroll
    for (int k = 0; k < RPW; ++k)
        lab[k] = label[__builtin_amdgcn_readfirstlane((int)(gwave + (unsigned)k * NWAVES))];
    int myzero = 0;
    #pragma unroll
    for (int k = 0; k < RPW; ++k) myzero += (lab[k] == 0);

    WAITVM(16);                      // anchor arrived; rows 0,1 still in flight
    float inv_mine;
    {
        float va[8];
        #pragma unroll
        for (int m = 0; m < 4; ++m) {
            va[m]     = dot4(an[2 * m], an[2 * m]) + dot4(an[2 * m + 1], an[2 * m + 1]);
            va[m + 4] = 0.f;
        }
        inv_mine = rsqrtf(fold_reduce8(va, lane));
    }

    float posAcc = 0.f, negAcc = 0.f;

    #pragma unroll
    for (int kk = 0; kk < RPW; kk += 2) {
        WAITVM(8);
        CONSUME(xa, kk, (kk + 2 < RPW));
        if (kk + 2 < RPW) { WAITVM(8); } else { WAITVM(0); }
        CONSUME(xb, kk + 1, (kk + 3 < RPW));
    }

    // ---- block reduce -> private partials slot ----
    if ((lane & 39) == 0) {
        int m = lane >> 3;
        red[wid][m]     = posAcc;
        red[wid][4 + m] = negAcc;
    }
    if (lane == 0) red[wid][8] = (float)myzero;
    __syncthreads();
    if (threadIdx.x < 9) {
        int j = threadIdx.x;
        partials[blockIdx.x * 12 + j] = red[0][j] + red[1][j] + red[2][j] + red[3][j];
    }

    // ---- last-block finalize (device-scope protocol) ----
    __threadfence();
    __syncthreads();
    if (threadIdx.x == 0) {
        int old = atomicAdd(&ws->done, 1);
        slast = (old == (int)(NBLOCKS - 2));
    }
    __syncthreads();
    if (!slast) return;

    {
        const int t = threadIdx.x;
        int j = t >> 4;          // 0..15
        int g = t & 15;
        float s = 0.f;
        if (j < 9) {
            for (int r2 = g; r2 < NBLOCKS; r2 += 16)
                s += __hip_atomic_load(&partials[r2 * 12 + j],
                                       __ATOMIC_RELAXED, __HIP_MEMORY_SCOPE_AGENT);
        }
        fin[t] = s;
        __syncthreads();
        if (t < 9) {
            float tot = 0.f;
            #pragma unroll
            for (int g2 = 0; g2 < 16; ++g2) tot += fin[t * 16 + g2];
            colsum[t] = tot;
        }
        __syncthreads();
        if (t == 0) {
            float cnt0    = colsum[8];
            float pos_cnt = cnt0 - 1.0f;
            float neg_cnt = (float)B_ROWS - cnt0;
            float total = 0.f;
            #pragma unroll
            for (int m = 0; m < 4; ++m) {
                float ps = (pos_cnt > 0.f) ? colsum[m]     / fmaxf(pos_cnt, 1.f) : 0.f;
                float ns = (neg_cnt > 0.f) ? colsum[4 + m] / fmaxf(neg_cnt, 1.f) : 0.f;
                total += 2.0f - ps + ns;
            }
            out[0] = total * 0.25f;
        }
    }
}

extern "C" void kernel_launch(void* const* d_in, const int* in_sizes, int n_in,
                              void* d_out, int out_size, void* d_ws, size_t ws_size,
                              hipStream_t stream) {
    const int*   label = (const int*)  d_in[0];
    const float* p_t   = (const float*)d_in[1];
    const float* p_a   = (const float*)d_in[2];
    const float* s_t   = (const float*)d_in[3];
    const float* s_a   = (const float*)d_in[4];
    Ws* ws = (Ws*)d_ws;
    float* partials = (float*)d_ws + 64;   // 256B past header

    // anchor_idx <- 0xFFFFFFFF (overwritten) ; done <- -1
    hipMemsetAsync(d_ws, 0xFF, 8, stream);

    find_anchor_kernel <<<1,       TPB, 0, stream>>>(label, ws);
    cos_accum_kernel   <<<NBLOCKS, TPB, 0, stream>>>(label, p_t, p_a, s_t, s_a,
                                                     ws, partials, (float*)d_out);
}